// Round 1
// baseline (279.371 us; speedup 1.0000x reference)
//
#include <hip/hip_runtime.h>

#define DD 128   // drug feature dim
#define HH 32    // hidden dim

__global__ __launch_bounds__(256)
void synergy_mlp_kernel(const float* __restrict__ drug,   // [N_DRUGS, 128]
                        const int*   __restrict__ edges,  // [E, 4] int32
                        const float* __restrict__ W1, const float* __restrict__ b1,
                        const float* __restrict__ W2, const float* __restrict__ b2,
                        const float* __restrict__ W3, const float* __restrict__ b3,
                        const float* __restrict__ W4, const float* __restrict__ b4,
                        float* __restrict__ out, int E)
{
    const int e = blockIdx.x * blockDim.x + threadIdx.x;
    if (e >= E) return;

    // Edge row: coalesced 16B load (lane i reads edges[e*4 .. e*4+3])
    const int4 ed = reinterpret_cast<const int4*>(edges)[e];

    const float4* __restrict__ r0 = reinterpret_cast<const float4*>(drug) + ed.x * (DD / 4);
    const float4* __restrict__ r1 = reinterpret_cast<const float4*>(drug) + ed.y * (DD / 4);
    const float4* __restrict__ r2 = reinterpret_cast<const float4*>(drug) + ed.z * (DD / 4);

    // ---- Layer 1: h1 = relu(logits @ W1^T + b1), logits[k] = d1[k]*d2[k]*dc[k]
    // k-loop is a genuine loop (16 iters, 8 k each) to keep code size small;
    // j fully unrolled so acc[] stays in VGPRs (constant indices only).
    float acc[HH];
    #pragma unroll
    for (int j = 0; j < HH; ++j) acc[j] = 0.0f;

    for (int kc = 0; kc < DD / 4; kc += 2) {
        const float4 a0 = r0[kc], a1 = r0[kc + 1];
        const float4 b0 = r1[kc], b1v = r1[kc + 1];
        const float4 c0 = r2[kc], c1 = r2[kc + 1];
        float l0 = a0.x * b0.x * c0.x;
        float l1 = a0.y * b0.y * c0.y;
        float l2 = a0.z * b0.z * c0.z;
        float l3 = a0.w * b0.w * c0.w;
        float l4 = a1.x * b1v.x * c1.x;
        float l5 = a1.y * b1v.y * c1.y;
        float l6 = a1.z * b1v.z * c1.z;
        float l7 = a1.w * b1v.w * c1.w;
        const int k0 = kc * 4;
        #pragma unroll
        for (int j = 0; j < HH; ++j) {
            // Uniform address (loop counters + uniform kernel arg) -> s_load,
            // weight rides in the SGPR operand of v_fma.
            const float* __restrict__ w = W1 + j * DD + k0;
            float t0 = fmaf(l0, w[0], fmaf(l1, w[1], fmaf(l2, w[2], l3 * w[3])));
            float t1 = fmaf(l4, w[4], fmaf(l5, w[5], fmaf(l6, w[6], l7 * w[7])));
            acc[j] += t0 + t1;
        }
    }

    float h1[HH];
    #pragma unroll
    for (int j = 0; j < HH; ++j) h1[j] = fmaxf(acc[j] + b1[j], 0.0f);

    // ---- Layer 2
    float h2[HH];
    #pragma unroll
    for (int j = 0; j < HH; ++j) {
        const float* __restrict__ w = W2 + j * HH;
        float s0 = 0.f, s1 = 0.f, s2 = 0.f, s3 = 0.f;
        #pragma unroll
        for (int k = 0; k < HH; k += 4) {
            s0 = fmaf(h1[k + 0], w[k + 0], s0);
            s1 = fmaf(h1[k + 1], w[k + 1], s1);
            s2 = fmaf(h1[k + 2], w[k + 2], s2);
            s3 = fmaf(h1[k + 3], w[k + 3], s3);
        }
        h2[j] = fmaxf(b2[j] + ((s0 + s1) + (s2 + s3)), 0.0f);
    }

    // ---- Layer 3
    float h3[HH];
    #pragma unroll
    for (int j = 0; j < HH; ++j) {
        const float* __restrict__ w = W3 + j * HH;
        float s0 = 0.f, s1 = 0.f, s2 = 0.f, s3 = 0.f;
        #pragma unroll
        for (int k = 0; k < HH; k += 4) {
            s0 = fmaf(h2[k + 0], w[k + 0], s0);
            s1 = fmaf(h2[k + 1], w[k + 1], s1);
            s2 = fmaf(h2[k + 2], w[k + 2], s2);
            s3 = fmaf(h2[k + 3], w[k + 3], s3);
        }
        h3[j] = fmaxf(b3[j] + ((s0 + s1) + (s2 + s3)), 0.0f);
    }

    // ---- Layer 4 + sigmoid
    float z = b4[0];
    {
        float s0 = 0.f, s1 = 0.f, s2 = 0.f, s3 = 0.f;
        #pragma unroll
        for (int k = 0; k < HH; k += 4) {
            s0 = fmaf(h3[k + 0], W4[k + 0], s0);
            s1 = fmaf(h3[k + 1], W4[k + 1], s1);
            s2 = fmaf(h3[k + 2], W4[k + 2], s2);
            s3 = fmaf(h3[k + 3], W4[k + 3], s3);
        }
        z += (s0 + s1) + (s2 + s3);
    }
    const float x = 1.0f / (1.0f + __expf(-z));

    // Output 0: sigmoid scores [E]; Output 1: labels as float [E]
    out[e]     = x;
    out[E + e] = (float)ed.w;
}

extern "C" void kernel_launch(void* const* d_in, const int* in_sizes, int n_in,
                              void* d_out, int out_size, void* d_ws, size_t ws_size,
                              hipStream_t stream)
{
    const float* drug = (const float*)d_in[0];
    // d_in[1] (cell_hidden_out), d_in[3] (proj_W), d_in[4] (proj_b) are dead
    // code in the reference: cell_fea indexes drug_hidden_out.
    const int*   edges = (const int*)d_in[2];
    const float* W1 = (const float*)d_in[5];
    const float* b1 = (const float*)d_in[6];
    const float* W2 = (const float*)d_in[7];
    const float* b2 = (const float*)d_in[8];
    const float* W3 = (const float*)d_in[9];
    const float* b3 = (const float*)d_in[10];
    const float* W4 = (const float*)d_in[11];
    const float* b4 = (const float*)d_in[12];
    float* out = (float*)d_out;

    const int E = in_sizes[2] / 4;   // all_edges is [E,4]
    dim3 block(256);
    dim3 grid((E + 255) / 256);
    hipLaunchKernelGGL(synergy_mlp_kernel, grid, block, 0, stream,
                       drug, edges, W1, b1, W2, b2, W3, b3, W4, b4, out, E);
}

// Round 2
// 193.502 us; speedup vs baseline: 1.4438x; 1.4438x over previous
//
#include <hip/hip_runtime.h>

#define DD 128   // drug feature dim
#define HH 32    // hidden dim
#define EPB 256  // edges per block (4 waves x 64)
#define HS 33    // LDS h-row stride (odd => conflict-free b32 column reads)

typedef __bf16 bf16x8 __attribute__((ext_vector_type(8)));
typedef float  f32x4  __attribute__((ext_vector_type(4)));

// Layer 1 via MFMA 16x16x32 bf16 (M=16 edges, N=16 hidden half, K=128 over 4 steps).
// Layers 2-4 per-lane fp32 VALU with scalar-loaded (uniform) weights.
__global__ __launch_bounds__(256)
void synergy_mfma_kernel(const float* __restrict__ drug,   // [N_DRUGS,128]
                         const int*   __restrict__ edges,  // [E,4]
                         const float* __restrict__ W1, const float* __restrict__ b1,
                         const float* __restrict__ W2, const float* __restrict__ b2,
                         const float* __restrict__ W3, const float* __restrict__ b3,
                         const float* __restrict__ W4, const float* __restrict__ b4,
                         float* __restrict__ out, int E)
{
    __shared__ float hbuf[EPB][HS];   // 256*33*4 = 33792 B

    const int tid  = threadIdx.x;
    const int wave = tid >> 6;
    const int lane = tid & 63;
    const int m    = lane & 15;   // A row (edge-in-tile) / B row (hidden n)
    const int q    = lane >> 4;   // quad: k-range q*8..q*8+7 within K=32 step

    const int blockBase = blockIdx.x * EPB;
    const int waveBase  = blockBase + wave * 64;

    const int4*   __restrict__ edges4 = reinterpret_cast<const int4*>(edges);
    const float4* __restrict__ drug4  = reinterpret_cast<const float4*>(drug);
    const float4* __restrict__ W1v    = reinterpret_cast<const float4*>(W1);

    // ---- Preload W1 as B-fragments: bw[tile][f] holds B[k=32f+8q+j][n=16*tile+m] = W1[n][k]
    bf16x8 bw[2][4];
    #pragma unroll
    for (int t = 0; t < 2; ++t) {
        #pragma unroll
        for (int f = 0; f < 4; ++f) {
            const int n  = t * 16 + m;
            const int c4 = (n * DD + f * 32 + q * 8) >> 2;  // float4 index
            const float4 w0 = W1v[c4];
            const float4 w1 = W1v[c4 + 1];
            bw[t][f][0] = (__bf16)w0.x; bw[t][f][1] = (__bf16)w0.y;
            bw[t][f][2] = (__bf16)w0.z; bw[t][f][3] = (__bf16)w0.w;
            bw[t][f][4] = (__bf16)w1.x; bw[t][f][5] = (__bf16)w1.y;
            bw[t][f][6] = (__bf16)w1.z; bw[t][f][7] = (__bf16)w1.w;
        }
    }
    const float bias0 = b1[m];
    const float bias1 = b1[16 + m];

    // ---- 4 m-tiles of 16 edges each (wave covers 64 edges)
    #pragma unroll
    for (int mt = 0; mt < 4; ++mt) {
        const int eIdx = waveBase + mt * 16 + m;
        const int eCl  = (eIdx < E) ? eIdx : (E - 1);
        const int4 ed  = edges4[eCl];

        const float4* __restrict__ r0 = drug4 + ed.x * (DD / 4);
        const float4* __restrict__ r1 = drug4 + ed.y * (DD / 4);
        const float4* __restrict__ r2 = drug4 + ed.z * (DD / 4);

        f32x4 acc0 = {0.f, 0.f, 0.f, 0.f};
        f32x4 acc1 = {0.f, 0.f, 0.f, 0.f};

        #pragma unroll
        for (int f = 0; f < 4; ++f) {
            const int c4 = f * 8 + q * 2;          // k0 = 32f + 8q
            const float4 a0 = r0[c4], a1 = r0[c4 + 1];
            const float4 d0 = r1[c4], d1 = r1[c4 + 1];
            const float4 c0 = r2[c4], c1 = r2[c4 + 1];
            bf16x8 af;
            af[0] = (__bf16)(a0.x * d0.x * c0.x);
            af[1] = (__bf16)(a0.y * d0.y * c0.y);
            af[2] = (__bf16)(a0.z * d0.z * c0.z);
            af[3] = (__bf16)(a0.w * d0.w * c0.w);
            af[4] = (__bf16)(a1.x * d1.x * c1.x);
            af[5] = (__bf16)(a1.y * d1.y * c1.y);
            af[6] = (__bf16)(a1.z * d1.z * c1.z);
            af[7] = (__bf16)(a1.w * d1.w * c1.w);
            acc0 = __builtin_amdgcn_mfma_f32_16x16x32_bf16(af, bw[0][f], acc0, 0, 0, 0);
            acc1 = __builtin_amdgcn_mfma_f32_16x16x32_bf16(af, bw[1][f], acc1, 0, 0, 0);
        }

        // Epilogue: lane holds D[edge=mt*16+4q+r][n=m(+16)]; bias+relu, park in LDS
        #pragma unroll
        for (int r = 0; r < 4; ++r) {
            const int erow = wave * 64 + mt * 16 + 4 * q + r;
            hbuf[erow][m]      = fmaxf(acc0[r] + bias0, 0.0f);
            hbuf[erow][16 + m] = fmaxf(acc1[r] + bias1, 0.0f);
        }
    }

    __syncthreads();

    // ---- Layers 2-4 per lane (edge = blockBase + tid), fp32, uniform weights -> s_load
    const int e = blockBase + tid;
    if (e >= E) return;

    float h1[HH];
    #pragma unroll
    for (int k = 0; k < HH; ++k) h1[k] = hbuf[tid][k];   // stride-33 b32, conflict-free

    float h2[HH];
    #pragma unroll
    for (int j = 0; j < HH; ++j) {
        const float* __restrict__ w = W2 + j * HH;
        float s0 = 0.f, s1 = 0.f, s2 = 0.f, s3 = 0.f;
        #pragma unroll
        for (int k = 0; k < HH; k += 4) {
            s0 = fmaf(h1[k + 0], w[k + 0], s0);
            s1 = fmaf(h1[k + 1], w[k + 1], s1);
            s2 = fmaf(h1[k + 2], w[k + 2], s2);
            s3 = fmaf(h1[k + 3], w[k + 3], s3);
        }
        h2[j] = fmaxf(b2[j] + ((s0 + s1) + (s2 + s3)), 0.0f);
    }

    float h3[HH];
    #pragma unroll
    for (int j = 0; j < HH; ++j) {
        const float* __restrict__ w = W3 + j * HH;
        float s0 = 0.f, s1 = 0.f, s2 = 0.f, s3 = 0.f;
        #pragma unroll
        for (int k = 0; k < HH; k += 4) {
            s0 = fmaf(h2[k + 0], w[k + 0], s0);
            s1 = fmaf(h2[k + 1], w[k + 1], s1);
            s2 = fmaf(h2[k + 2], w[k + 2], s2);
            s3 = fmaf(h2[k + 3], w[k + 3], s3);
        }
        h3[j] = fmaxf(b3[j] + ((s0 + s1) + (s2 + s3)), 0.0f);
    }

    float z = b4[0];
    {
        float s0 = 0.f, s1 = 0.f, s2 = 0.f, s3 = 0.f;
        #pragma unroll
        for (int k = 0; k < HH; k += 4) {
            s0 = fmaf(h3[k + 0], W4[k + 0], s0);
            s1 = fmaf(h3[k + 1], W4[k + 1], s1);
            s2 = fmaf(h3[k + 2], W4[k + 2], s2);
            s3 = fmaf(h3[k + 3], W4[k + 3], s3);
        }
        z += (s0 + s1) + (s2 + s3);
    }
    const float x = 1.0f / (1.0f + __expf(-z));

    out[e]     = x;
    out[E + e] = (float)edges4[e].w;   // label pass-through
}

extern "C" void kernel_launch(void* const* d_in, const int* in_sizes, int n_in,
                              void* d_out, int out_size, void* d_ws, size_t ws_size,
                              hipStream_t stream)
{
    const float* drug  = (const float*)d_in[0];
    // d_in[1] (cell_hidden_out), d_in[3] (proj_W), d_in[4] (proj_b): dead code
    const int*   edges = (const int*)d_in[2];
    const float* W1 = (const float*)d_in[5];
    const float* b1 = (const float*)d_in[6];
    const float* W2 = (const float*)d_in[7];
    const float* b2 = (const float*)d_in[8];
    const float* W3 = (const float*)d_in[9];
    const float* b3 = (const float*)d_in[10];
    const float* W4 = (const float*)d_in[11];
    const float* b4 = (const float*)d_in[12];
    float* out = (float*)d_out;

    const int E = in_sizes[2] / 4;
    dim3 block(256);
    dim3 grid((E + EPB - 1) / EPB);
    hipLaunchKernelGGL(synergy_mfma_kernel, grid, block, 0, stream,
                       drug, edges, W1, b1, W2, b2, W3, b3, W4, b4, out, E);
}